// Round 1
// baseline (910.754 us; speedup 1.0000x reference)
//
#include <hip/hip_runtime.h>
#include <cstdint>
#include <cstddef>

// Problem dims (fixed by reference)
#define BDIM 512
#define SDIM 64
#define DDIM 256
#define D2   512
#define NNODE 100000
#define NM1  99999   // logits columns

typedef short short8 __attribute__((ext_vector_type(8)));
typedef float f32x4 __attribute__((ext_vector_type(4)));

__device__ __forceinline__ unsigned short f2bf(float f) {
  unsigned int u = __float_as_uint(f);
  u += 0x7FFFu + ((u >> 16) & 1u);   // RNE
  return (unsigned short)(u >> 16);
}

// ---------------------------------------------------------------------------
// Kernel 1: per-batch prep. Only row s* = alias[b, rm-1] is used downstream.
// av[b, 0:256] = adj_in[b,s*,:] @ emb[item[b,:]]; av[b,256:512] = adj_out row.
// Mask sum wave-parallelized (was 64 serial loads on thread 0).
// ---------------------------------------------------------------------------
__global__ __launch_bounds__(256) void prep_kernel(
    const float* __restrict__ emb, const float* __restrict__ adj_in,
    const float* __restrict__ adj_out, const float* __restrict__ mask,
    const int* __restrict__ item, const int* __restrict__ alias_,
    float* __restrict__ av) {
  __shared__ float a_in[SDIM], a_out[SDIM];
  __shared__ int it[SDIM];
  __shared__ int s_star;
  const int b = blockIdx.x, t = threadIdx.x;
  if (t < SDIM) it[t] = item[b * SDIM + t];
  if (t < 64) {
    float m = mask[b * SDIM + t];
#pragma unroll
    for (int off = 32; off > 0; off >>= 1) m += __shfl_down(m, off, 64);
    if (t == 0) {
      int rm = (int)m;                     // matches astype(int32) truncation
      s_star = alias_[b * SDIM + rm - 1];
    }
  }
  __syncthreads();
  const int ss = s_star;
  if (t < SDIM) a_in[t] = adj_in[((size_t)b * SDIM + ss) * SDIM + t];
  else if (t < 2 * SDIM) a_out[t - SDIM] = adj_out[((size_t)b * SDIM + ss) * SDIM + (t - SDIM)];
  __syncthreads();
  const int d = t;  // 256 threads == DDIM
  float ai = 0.f, ao = 0.f;
#pragma unroll 8
  for (int j = 0; j < SDIM; j++) {
    float e = emb[(size_t)it[j] * DDIM + d];  // coalesced across d
    ai = fmaf(a_in[j], e, ai);
    ao = fmaf(a_out[j], e, ao);
  }
  av[(size_t)b * D2 + d] = ai;
  av[(size_t)b * D2 + DDIM + d] = ao;
}

// ---------------------------------------------------------------------------
// Kernels 2+3: fp32 GEMM, tile 32(M) x 64(N), 256 threads, 4x2 micro-tile.
// 8 FMA per 3 LDS reads (vs 16:16 in old naive 16x16 version).
// mlp1: O = relu(A@W1) f32;  mlp2: O = (A@W2) -> bf16.
// ---------------------------------------------------------------------------
template <int N, bool RELU, bool OUTBF16>
__global__ __launch_bounds__(256) void mlp_kernel(
    const float* __restrict__ A, const float* __restrict__ W,
    float* __restrict__ Of, unsigned short* __restrict__ Ob) {
  __shared__ float As[32][36];   // [m][k]  (36: float4-aligned, bank-friendly)
  __shared__ float Bs[32][68];   // [k][n]
  const int tx = threadIdx.x, ty = threadIdx.y;  // 16x16
  const int t = ty * 16 + tx;
  const int row0 = blockIdx.y * 32, col0 = blockIdx.x * 64;
  const int ar = t >> 3, ac = (t & 7) * 4;   // As: 32x32 = 4 f32/thread
  const int kr = t >> 4, bc = (t & 15) * 4;  // Bs: 32x64 = 8 f32/thread
  float acc[2][4];
#pragma unroll
  for (int i = 0; i < 2; i++)
#pragma unroll
    for (int j = 0; j < 4; j++) acc[i][j] = 0.f;

  for (int k0 = 0; k0 < D2; k0 += 32) {
    const float4 a4 = *(const float4*)&A[(size_t)(row0 + ar) * D2 + k0 + ac];
    const float4 b4a = *(const float4*)&W[(size_t)(k0 + kr) * N + col0 + bc];
    const float4 b4b = *(const float4*)&W[(size_t)(k0 + kr + 16) * N + col0 + bc];
    *(float4*)&As[ar][ac] = a4;
    *(float4*)&Bs[kr][bc] = b4a;
    *(float4*)&Bs[kr + 16][bc] = b4b;
    __syncthreads();
#pragma unroll
    for (int k = 0; k < 32; k++) {
      const float a0 = As[ty * 2][k];
      const float a1 = As[ty * 2 + 1][k];
      const float4 bv = *(const float4*)&Bs[k][tx * 4];
      acc[0][0] = fmaf(a0, bv.x, acc[0][0]); acc[0][1] = fmaf(a0, bv.y, acc[0][1]);
      acc[0][2] = fmaf(a0, bv.z, acc[0][2]); acc[0][3] = fmaf(a0, bv.w, acc[0][3]);
      acc[1][0] = fmaf(a1, bv.x, acc[1][0]); acc[1][1] = fmaf(a1, bv.y, acc[1][1]);
      acc[1][2] = fmaf(a1, bv.z, acc[1][2]); acc[1][3] = fmaf(a1, bv.w, acc[1][3]);
    }
    __syncthreads();
  }
#pragma unroll
  for (int i = 0; i < 2; i++) {
    const int row = row0 + ty * 2 + i;
    const int col = col0 + tx * 4;
    float4 r4;
    r4.x = acc[i][0]; r4.y = acc[i][1]; r4.z = acc[i][2]; r4.w = acc[i][3];
    if constexpr (RELU) {
      r4.x = fmaxf(r4.x, 0.f); r4.y = fmaxf(r4.y, 0.f);
      r4.z = fmaxf(r4.z, 0.f); r4.w = fmaxf(r4.w, 0.f);
    }
    if constexpr (OUTBF16) {
      ushort4 p;
      p.x = f2bf(r4.x); p.y = f2bf(r4.y); p.z = f2bf(r4.z); p.w = f2bf(r4.w);
      *(ushort4*)&Ob[(size_t)row * N + col] = p;
    } else {
      *(float4*)&Of[(size_t)row * N + col] = r4;
    }
  }
}

// ---------------------------------------------------------------------------
// Kernel 4: logits[512, 99999] = last_h(bf16) @ emb[1:]^T  (bf16 MFMA)
// Restructured: one block per 64-col n-strip, FULL M=512 per block.
//  - B (emb rows) staged ONCE per block into LDS, full K=256 resident.
//    Pad 264 shorts/row: stride 528 B = 33*16 (16B-aligned b128 reads,
//    4-bank row advance -> minimum aliasing).
//  - A fragments read directly from global (lasth = 256 KB, L2-resident).
//    No A-LDS -> 33.8 KB LDS -> 4 blocks/CU (16 waves), 1 barrier/block.
//  - Non-temporal logits stores: don't thrash L2/L3 (emb read exactly once).
// Fused epilogue: per-row sum of exp(logit) -> atomicAdd into rse[512].
// ---------------------------------------------------------------------------
#define NT    64
#define BPAD  264
#define NTILES 1563   // ceil(99999 / 64)

__global__ __launch_bounds__(256, 4) void logits_gemm(
    const unsigned short* __restrict__ Abf,  // [512,256] bf16
    const float* __restrict__ emb,           // [100000,256] f32
    float* __restrict__ out,                 // d_out: [0]=loss, [1..]=logits
    float* __restrict__ rse) {               // [512] running sum-exp
  __shared__ short Bs[NT * BPAD];
  const int t = threadIdx.x;
  const int lane = t & 63, w = t >> 6;
  const int nbase = blockIdx.x * NT;

  // ---- stage B: 64 emb rows (cols n+1), f32 -> bf16, once per block
  {
    const int r0 = w * 16;  // each of 4 waves stages 16 rows; 1 float4/lane/row
#pragma unroll 4
    for (int i = 0; i < 16; i++) {
      const int row = r0 + i;
      int er = nbase + row + 1;
      if (er > NM1) er = NM1;  // clamp; invalid cols masked in epilogue
      const float4 v = *(const float4*)(emb + (size_t)er * DDIM + lane * 4);
      ushort4 p;
      p.x = f2bf(v.x); p.y = f2bf(v.y); p.z = f2bf(v.z); p.w = f2bf(v.w);
      *(ushort4*)&Bs[row * BPAD + lane * 4] = p;
    }
  }
  __syncthreads();

  const int wm = (w >> 1) * 64;   // wave tile: 64 rows x 32 cols
  const int wn = (w & 1) * 32;
  const int c = lane & 15, q = lane >> 4;

  for (int m = 0; m < 4; m++) {   // 4 x 128-row M-tiles = full M=512
    f32x4 acc[4][2];
#pragma unroll
    for (int mi = 0; mi < 4; mi++)
#pragma unroll
      for (int ni = 0; ni < 2; ni++) acc[mi][ni] = (f32x4){0.f, 0.f, 0.f, 0.f};

#pragma unroll
    for (int ks = 0; ks < 8; ks++) {   // K = 256 in steps of 32
      short8 afr[4], bfr[2];
#pragma unroll
      for (int mi = 0; mi < 4; mi++)
        afr[mi] = *(const short8*)(Abf +
            (size_t)(m * 128 + wm + mi * 16 + c) * DDIM + ks * 32 + q * 8);
#pragma unroll
      for (int ni = 0; ni < 2; ni++)
        bfr[ni] = *(const short8*)&Bs[(wn + ni * 16 + c) * BPAD + ks * 32 + q * 8];
#pragma unroll
      for (int mi = 0; mi < 4; mi++)
#pragma unroll
        for (int ni = 0; ni < 2; ni++)
          acc[mi][ni] = __builtin_amdgcn_mfma_f32_16x16x32_bf16(
              afr[mi], bfr[ni], acc[mi][ni], 0, 0, 0);
    }

    // Epilogue for this m-tile: NT stores + per-row partial sum-exp.
#pragma unroll
    for (int mi = 0; mi < 4; mi++) {
#pragma unroll
      for (int r = 0; r < 4; r++) {
        const int grow = m * 128 + wm + mi * 16 + q * 4 + r;  // row = q*4+reg
        float s = 0.f;
#pragma unroll
        for (int ni = 0; ni < 2; ni++) {
          const int col = nbase + wn + ni * 16 + c;           // col = lane&15
          if (col < NM1) {
            const float v = acc[mi][ni][r];
            __builtin_nontemporal_store(v, &out[1 + (size_t)grow * NM1 + col]);
            s += __expf(v);
          }
        }
#pragma unroll
        for (int msk = 1; msk < 16; msk <<= 1) s += __shfl_xor(s, msk, 64);
        if (c == 0) atomicAdd(&rse[grow], s);
      }
    }
  }
}

// ---------------------------------------------------------------------------
// Kernel 5: loss = mean_b( log(sum_exp[b]) - logits[b, tar[b]-1] )
// ---------------------------------------------------------------------------
__global__ __launch_bounds__(512) void loss_kernel(
    float* __restrict__ out, const float* __restrict__ rse,
    const int* __restrict__ tar) {
  __shared__ float red[512];
  const int t = threadIdx.x;
  const int tt = tar[t];
  const float lg = out[1 + (size_t)t * NM1 + (tt - 1)];
  red[t] = logf(rse[t]) - lg;
  __syncthreads();
  for (int stride = 256; stride > 0; stride >>= 1) {
    if (t < stride) red[t] += red[t + stride];
    __syncthreads();
  }
  if (t == 0) out[0] = red[0] / (float)BDIM;
}

// ---------------------------------------------------------------------------
extern "C" void kernel_launch(void* const* d_in, const int* in_sizes, int n_in,
                              void* d_out, int out_size, void* d_ws, size_t ws_size,
                              hipStream_t stream) {
  const float* emb     = (const float*)d_in[0];
  const float* W1      = (const float*)d_in[1];
  const float* W2      = (const float*)d_in[2];
  const float* adj_in  = (const float*)d_in[3];
  const float* adj_out = (const float*)d_in[4];
  const float* mask    = (const float*)d_in[5];
  const int*   item    = (const int*)d_in[6];
  const int*   alias_  = (const int*)d_in[7];
  const int*   tar     = (const int*)d_in[8];
  float* out = (float*)d_out;

  char* ws = (char*)d_ws;
  float* av            = (float*)(ws);                 // 512*512*4 = 1 MB
  float* h1            = (float*)(ws + 1048576);       // 512*512*4 = 1 MB
  unsigned short* lasth = (unsigned short*)(ws + 2097152); // 512*256*2 = 256 KB
  float* rse           = (float*)(ws + 2359296);       // 512*4

  hipMemsetAsync(rse, 0, BDIM * sizeof(float), stream);
  prep_kernel<<<BDIM, 256, 0, stream>>>(emb, adj_in, adj_out, mask, item, alias_, av);
  mlp_kernel<D2, true, false><<<dim3(8, 16), dim3(16, 16), 0, stream>>>(av, W1, h1, nullptr);
  mlp_kernel<DDIM, false, true><<<dim3(4, 16), dim3(16, 16), 0, stream>>>(h1, W2, nullptr, lasth);
  logits_gemm<<<dim3(NTILES), 256, 0, stream>>>(lasth, emb, out, rse);
  loss_kernel<<<1, 512, 0, stream>>>(out, rse, tar);
}

// Round 3
// 515.770 us; speedup vs baseline: 1.7658x; 1.7658x over previous
//
#include <hip/hip_runtime.h>
#include <cstdint>
#include <cstddef>

// Problem dims (fixed by reference)
#define BDIM 512
#define SDIM 64
#define DDIM 256
#define D2   512
#define NNODE 100000
#define NM1  99999   // logits columns

typedef short short8 __attribute__((ext_vector_type(8)));
typedef float f32x4 __attribute__((ext_vector_type(4)));

__device__ __forceinline__ unsigned short f2bf(float f) {
  unsigned int u = __float_as_uint(f);
  u += 0x7FFFu + ((u >> 16) & 1u);   // RNE
  return (unsigned short)(u >> 16);
}

// ---------------------------------------------------------------------------
// Kernel 1: per-batch prep. Only row s* = alias[b, rm-1] is used downstream.
// av[b, 0:256] = adj_in[b,s*,:] @ emb[item[b,:]]; av[b,256:512] = adj_out row.
// ---------------------------------------------------------------------------
__global__ __launch_bounds__(256) void prep_kernel(
    const float* __restrict__ emb, const float* __restrict__ adj_in,
    const float* __restrict__ adj_out, const float* __restrict__ mask,
    const int* __restrict__ item, const int* __restrict__ alias_,
    float* __restrict__ av) {
  __shared__ float a_in[SDIM], a_out[SDIM];
  __shared__ int it[SDIM];
  __shared__ int s_star;
  const int b = blockIdx.x, t = threadIdx.x;
  if (t < SDIM) it[t] = item[b * SDIM + t];
  if (t < 64) {
    float m = mask[b * SDIM + t];
#pragma unroll
    for (int off = 32; off > 0; off >>= 1) m += __shfl_down(m, off, 64);
    if (t == 0) {
      int rm = (int)m;                     // matches astype(int32) truncation
      s_star = alias_[b * SDIM + rm - 1];
    }
  }
  __syncthreads();
  const int ss = s_star;
  if (t < SDIM) a_in[t] = adj_in[((size_t)b * SDIM + ss) * SDIM + t];
  else if (t < 2 * SDIM) a_out[t - SDIM] = adj_out[((size_t)b * SDIM + ss) * SDIM + (t - SDIM)];
  __syncthreads();
  const int d = t;  // 256 threads == DDIM
  float ai = 0.f, ao = 0.f;
#pragma unroll 8
  for (int j = 0; j < SDIM; j++) {
    float e = emb[(size_t)it[j] * DDIM + d];  // coalesced across d
    ai = fmaf(a_in[j], e, ai);
    ao = fmaf(a_out[j], e, ao);
  }
  av[(size_t)b * D2 + d] = ai;
  av[(size_t)b * D2 + DDIM + d] = ao;
}

// ---------------------------------------------------------------------------
// Kernels 2+3: fp32 GEMM, tile 32(M) x 64(N), 256 threads, 4x2 micro-tile.
// mlp1: O = relu(A@W1) f32;  mlp2: O = (A@W2) -> bf16.
// ---------------------------------------------------------------------------
template <int N, bool RELU, bool OUTBF16>
__global__ __launch_bounds__(256) void mlp_kernel(
    const float* __restrict__ A, const float* __restrict__ W,
    float* __restrict__ Of, unsigned short* __restrict__ Ob) {
  __shared__ float As[32][36];   // [m][k]
  __shared__ float Bs[32][68];   // [k][n]
  const int tx = threadIdx.x, ty = threadIdx.y;  // 16x16
  const int t = ty * 16 + tx;
  const int row0 = blockIdx.y * 32, col0 = blockIdx.x * 64;
  const int ar = t >> 3, ac = (t & 7) * 4;   // As: 32x32 = 4 f32/thread
  const int kr = t >> 4, bc = (t & 15) * 4;  // Bs: 32x64 = 8 f32/thread
  float acc[2][4];
#pragma unroll
  for (int i = 0; i < 2; i++)
#pragma unroll
    for (int j = 0; j < 4; j++) acc[i][j] = 0.f;

  for (int k0 = 0; k0 < D2; k0 += 32) {
    const float4 a4 = *(const float4*)&A[(size_t)(row0 + ar) * D2 + k0 + ac];
    const float4 b4a = *(const float4*)&W[(size_t)(k0 + kr) * N + col0 + bc];
    const float4 b4b = *(const float4*)&W[(size_t)(k0 + kr + 16) * N + col0 + bc];
    *(float4*)&As[ar][ac] = a4;
    *(float4*)&Bs[kr][bc] = b4a;
    *(float4*)&Bs[kr + 16][bc] = b4b;
    __syncthreads();
#pragma unroll
    for (int k = 0; k < 32; k++) {
      const float a0 = As[ty * 2][k];
      const float a1 = As[ty * 2 + 1][k];
      const float4 bv = *(const float4*)&Bs[k][tx * 4];
      acc[0][0] = fmaf(a0, bv.x, acc[0][0]); acc[0][1] = fmaf(a0, bv.y, acc[0][1]);
      acc[0][2] = fmaf(a0, bv.z, acc[0][2]); acc[0][3] = fmaf(a0, bv.w, acc[0][3]);
      acc[1][0] = fmaf(a1, bv.x, acc[1][0]); acc[1][1] = fmaf(a1, bv.y, acc[1][1]);
      acc[1][2] = fmaf(a1, bv.z, acc[1][2]); acc[1][3] = fmaf(a1, bv.w, acc[1][3]);
    }
    __syncthreads();
  }
#pragma unroll
  for (int i = 0; i < 2; i++) {
    const int row = row0 + ty * 2 + i;
    const int col = col0 + tx * 4;
    float4 r4;
    r4.x = acc[i][0]; r4.y = acc[i][1]; r4.z = acc[i][2]; r4.w = acc[i][3];
    if constexpr (RELU) {
      r4.x = fmaxf(r4.x, 0.f); r4.y = fmaxf(r4.y, 0.f);
      r4.z = fmaxf(r4.z, 0.f); r4.w = fmaxf(r4.w, 0.f);
    }
    if constexpr (OUTBF16) {
      ushort4 p;
      p.x = f2bf(r4.x); p.y = f2bf(r4.y); p.z = f2bf(r4.z); p.w = f2bf(r4.w);
      *(ushort4*)&Ob[(size_t)row * N + col] = p;
    } else {
      *(float4*)&Of[(size_t)row * N + col] = r4;
    }
  }
}

// ---------------------------------------------------------------------------
// Kernel 4: logits[512, 99999] = last_h(bf16) @ emb[1:]^T  (bf16 MFMA)
// One block per 64-col n-strip, FULL M=512, 8 waves (512 threads).
//  - B (64 emb rows, K=256) staged ONCE into LDS (f32->bf16), one barrier.
//    Row stride 264 shorts: 16B-aligned b128 reads.
//  - Wave w owns rows w*64..w*64+63 x all 64 cols: acc[4][4], no outer loop.
//    ks-loop fully unrolled -> scheduler pipelines the 32 L2 A-loads.
//  - NORMAL stores (round-1 lesson: NT partial-line stores = 1.8x write
//    amplification, 370 MB vs 223 MB).
//  - emb read exactly once from HBM (round-1 lesson kept: FETCH 136 MB).
// Fused epilogue: per-row sum of exp(logit) -> atomicAdd into rse[512]
// (round-0-proven at this atomic volume).
// ---------------------------------------------------------------------------
#define NT    64
#define BPAD  264
#define NTILES 1563   // ceil(99999 / 64)

__global__ __launch_bounds__(512, 4) void logits_gemm(
    const unsigned short* __restrict__ Abf,  // [512,256] bf16
    const float* __restrict__ emb,           // [100000,256] f32
    float* __restrict__ out,                 // d_out: [0]=loss, [1..]=logits
    float* __restrict__ rse) {               // [512] running sum-exp
  __shared__ short Bs[NT * BPAD];            // 33792 B
  const int t = threadIdx.x;
  const int lane = t & 63, w = t >> 6;       // 8 waves
  const int nbase = blockIdx.x * NT;

  // ---- stage B: 64 emb rows (cols n+1), f32 -> bf16, once per block.
  // row = t>>3, 8 threads/row; per j the 8 threads cover 128B contiguous.
  {
    const int row = t >> 3;
    const int cb = (t & 7) * 4;
    int er = nbase + row + 1;
    if (er > NM1) er = NM1;  // clamp; invalid cols masked in epilogue
    const float* src = emb + (size_t)er * DDIM;
    short* dst = &Bs[row * BPAD];
#pragma unroll
    for (int j = 0; j < 8; j++) {
      const float4 v = *(const float4*)(src + j * 32 + cb);
      ushort4 p;
      p.x = f2bf(v.x); p.y = f2bf(v.y); p.z = f2bf(v.z); p.w = f2bf(v.w);
      *(ushort4*)&dst[j * 32 + cb] = p;
    }
  }
  __syncthreads();

  const int wm = w * 64;            // wave tile: 64 rows x 64 cols
  const int c = lane & 15, q = lane >> 4;

  f32x4 acc[4][4];
#pragma unroll
  for (int mi = 0; mi < 4; mi++)
#pragma unroll
    for (int ni = 0; ni < 4; ni++) acc[mi][ni] = (f32x4){0.f, 0.f, 0.f, 0.f};

#pragma unroll
  for (int ks = 0; ks < 8; ks++) {   // K = 256 in steps of 32, fully unrolled
    short8 afr[4], bfr[4];
#pragma unroll
    for (int mi = 0; mi < 4; mi++)
      afr[mi] = *(const short8*)(Abf +
          (size_t)(wm + mi * 16 + c) * DDIM + ks * 32 + q * 8);
#pragma unroll
    for (int ni = 0; ni < 4; ni++)
      bfr[ni] = *(const short8*)&Bs[(ni * 16 + c) * BPAD + ks * 32 + q * 8];
#pragma unroll
    for (int mi = 0; mi < 4; mi++)
#pragma unroll
      for (int ni = 0; ni < 4; ni++)
        acc[mi][ni] = __builtin_amdgcn_mfma_f32_16x16x32_bf16(
            afr[mi], bfr[ni], acc[mi][ni], 0, 0, 0);
  }

  // Epilogue: normal scalar stores + per-row partial sum of exp,
  // reduced over the 16 col-lanes (c), atomicAdd once per row per block.
#pragma unroll
  for (int mi = 0; mi < 4; mi++) {
#pragma unroll
    for (int r = 0; r < 4; r++) {
      const int grow = wm + mi * 16 + q * 4 + r;  // C/D: row = q*4+reg
      float s = 0.f;
#pragma unroll
      for (int ni = 0; ni < 4; ni++) {
        const int col = nbase + ni * 16 + c;      // C/D: col = lane&15
        if (col < NM1) {
          const float v = acc[mi][ni][r];
          out[1 + (size_t)grow * NM1 + col] = v;
          s += __expf(v);
        }
      }
#pragma unroll
      for (int msk = 1; msk < 16; msk <<= 1) s += __shfl_xor(s, msk, 64);
      if (c == 0) atomicAdd(&rse[grow], s);
    }
  }
}

// ---------------------------------------------------------------------------
// Kernel 5: loss = mean_b( log(sum_exp[b]) - logits[b, tar[b]-1] )
// ---------------------------------------------------------------------------
__global__ __launch_bounds__(512) void loss_kernel(
    float* __restrict__ out, const float* __restrict__ rse,
    const int* __restrict__ tar) {
  __shared__ float red[512];
  const int t = threadIdx.x;
  const int tt = tar[t];
  const float lg = out[1 + (size_t)t * NM1 + (tt - 1)];
  red[t] = logf(rse[t]) - lg;
  __syncthreads();
  for (int stride = 256; stride > 0; stride >>= 1) {
    if (t < stride) red[t] += red[t + stride];
    __syncthreads();
  }
  if (t == 0) out[0] = red[0] / (float)BDIM;
}

// ---------------------------------------------------------------------------
extern "C" void kernel_launch(void* const* d_in, const int* in_sizes, int n_in,
                              void* d_out, int out_size, void* d_ws, size_t ws_size,
                              hipStream_t stream) {
  const float* emb     = (const float*)d_in[0];
  const float* W1      = (const float*)d_in[1];
  const float* W2      = (const float*)d_in[2];
  const float* adj_in  = (const float*)d_in[3];
  const float* adj_out = (const float*)d_in[4];
  const float* mask    = (const float*)d_in[5];
  const int*   item    = (const int*)d_in[6];
  const int*   alias_  = (const int*)d_in[7];
  const int*   tar     = (const int*)d_in[8];
  float* out = (float*)d_out;

  char* ws = (char*)d_ws;
  float* av            = (float*)(ws);                 // 512*512*4 = 1 MB
  float* h1            = (float*)(ws + 1048576);       // 512*512*4 = 1 MB
  unsigned short* lasth = (unsigned short*)(ws + 2097152); // 512*256*2 = 256 KB
  float* rse           = (float*)(ws + 2359296);       // 512*4

  hipMemsetAsync(rse, 0, BDIM * sizeof(float), stream);
  prep_kernel<<<BDIM, 256, 0, stream>>>(emb, adj_in, adj_out, mask, item, alias_, av);
  mlp_kernel<D2, true, false><<<dim3(8, 16), dim3(16, 16), 0, stream>>>(av, W1, h1, nullptr);
  mlp_kernel<DDIM, false, true><<<dim3(4, 16), dim3(16, 16), 0, stream>>>(h1, W2, nullptr, lasth);
  logits_gemm<<<dim3(NTILES), 512, 0, stream>>>(lasth, emb, out, rse);
  loss_kernel<<<1, 512, 0, stream>>>(out, rse, tar);
}

// Round 4
// 456.546 us; speedup vs baseline: 1.9949x; 1.1297x over previous
//
#include <hip/hip_runtime.h>
#include <cstdint>
#include <cstddef>

// Problem dims (fixed by reference)
#define BDIM 512
#define SDIM 64
#define DDIM 256
#define D2   512
#define NNODE 100000
#define NM1  99999   // logits columns

typedef short short8 __attribute__((ext_vector_type(8)));
typedef float f32x4 __attribute__((ext_vector_type(4)));

__device__ __forceinline__ unsigned short f2bf(float f) {
  unsigned int u = __float_as_uint(f);
  u += 0x7FFFu + ((u >> 16) & 1u);   // RNE
  return (unsigned short)(u >> 16);
}

// ---------------------------------------------------------------------------
// Kernel 1: per-batch prep. Only row s* = alias[b, rm-1] is used downstream.
// av[b, 0:256] = adj_in[b,s*,:] @ emb[item[b,:]]; av[b,256:512] = adj_out row.
// ---------------------------------------------------------------------------
__global__ __launch_bounds__(256) void prep_kernel(
    const float* __restrict__ emb, const float* __restrict__ adj_in,
    const float* __restrict__ adj_out, const float* __restrict__ mask,
    const int* __restrict__ item, const int* __restrict__ alias_,
    float* __restrict__ av) {
  __shared__ float a_in[SDIM], a_out[SDIM];
  __shared__ int it[SDIM];
  __shared__ int s_star;
  const int b = blockIdx.x, t = threadIdx.x;
  if (t < SDIM) it[t] = item[b * SDIM + t];
  if (t < 64) {
    float m = mask[b * SDIM + t];
#pragma unroll
    for (int off = 32; off > 0; off >>= 1) m += __shfl_down(m, off, 64);
    if (t == 0) {
      int rm = (int)m;                     // matches astype(int32) truncation
      s_star = alias_[b * SDIM + rm - 1];
    }
  }
  __syncthreads();
  const int ss = s_star;
  if (t < SDIM) a_in[t] = adj_in[((size_t)b * SDIM + ss) * SDIM + t];
  else if (t < 2 * SDIM) a_out[t - SDIM] = adj_out[((size_t)b * SDIM + ss) * SDIM + (t - SDIM)];
  __syncthreads();
  const int d = t;  // 256 threads == DDIM
  float ai = 0.f, ao = 0.f;
#pragma unroll 8
  for (int j = 0; j < SDIM; j++) {
    float e = emb[(size_t)it[j] * DDIM + d];  // coalesced across d
    ai = fmaf(a_in[j], e, ai);
    ao = fmaf(a_out[j], e, ao);
  }
  av[(size_t)b * D2 + d] = ai;
  av[(size_t)b * D2 + DDIM + d] = ao;
}

// ---------------------------------------------------------------------------
// Kernels 2+3: fp32 GEMM, tile 32(M) x 64(N), 256 threads, 4x2 micro-tile.
// mlp1: O = relu(A@W1) f32;  mlp2: O = (A@W2) -> bf16.
// ---------------------------------------------------------------------------
template <int N, bool RELU, bool OUTBF16>
__global__ __launch_bounds__(256) void mlp_kernel(
    const float* __restrict__ A, const float* __restrict__ W,
    float* __restrict__ Of, unsigned short* __restrict__ Ob) {
  __shared__ float As[32][36];   // [m][k]
  __shared__ float Bs[32][68];   // [k][n]
  const int tx = threadIdx.x, ty = threadIdx.y;  // 16x16
  const int t = ty * 16 + tx;
  const int row0 = blockIdx.y * 32, col0 = blockIdx.x * 64;
  const int ar = t >> 3, ac = (t & 7) * 4;   // As: 32x32 = 4 f32/thread
  const int kr = t >> 4, bc = (t & 15) * 4;  // Bs: 32x64 = 8 f32/thread
  float acc[2][4];
#pragma unroll
  for (int i = 0; i < 2; i++)
#pragma unroll
    for (int j = 0; j < 4; j++) acc[i][j] = 0.f;

  for (int k0 = 0; k0 < D2; k0 += 32) {
    const float4 a4 = *(const float4*)&A[(size_t)(row0 + ar) * D2 + k0 + ac];
    const float4 b4a = *(const float4*)&W[(size_t)(k0 + kr) * N + col0 + bc];
    const float4 b4b = *(const float4*)&W[(size_t)(k0 + kr + 16) * N + col0 + bc];
    *(float4*)&As[ar][ac] = a4;
    *(float4*)&Bs[kr][bc] = b4a;
    *(float4*)&Bs[kr + 16][bc] = b4b;
    __syncthreads();
#pragma unroll
    for (int k = 0; k < 32; k++) {
      const float a0 = As[ty * 2][k];
      const float a1 = As[ty * 2 + 1][k];
      const float4 bv = *(const float4*)&Bs[k][tx * 4];
      acc[0][0] = fmaf(a0, bv.x, acc[0][0]); acc[0][1] = fmaf(a0, bv.y, acc[0][1]);
      acc[0][2] = fmaf(a0, bv.z, acc[0][2]); acc[0][3] = fmaf(a0, bv.w, acc[0][3]);
      acc[1][0] = fmaf(a1, bv.x, acc[1][0]); acc[1][1] = fmaf(a1, bv.y, acc[1][1]);
      acc[1][2] = fmaf(a1, bv.z, acc[1][2]); acc[1][3] = fmaf(a1, bv.w, acc[1][3]);
    }
    __syncthreads();
  }
#pragma unroll
  for (int i = 0; i < 2; i++) {
    const int row = row0 + ty * 2 + i;
    const int col = col0 + tx * 4;
    float4 r4;
    r4.x = acc[i][0]; r4.y = acc[i][1]; r4.z = acc[i][2]; r4.w = acc[i][3];
    if constexpr (RELU) {
      r4.x = fmaxf(r4.x, 0.f); r4.y = fmaxf(r4.y, 0.f);
      r4.z = fmaxf(r4.z, 0.f); r4.w = fmaxf(r4.w, 0.f);
    }
    if constexpr (OUTBF16) {
      ushort4 p;
      p.x = f2bf(r4.x); p.y = f2bf(r4.y); p.z = f2bf(r4.z); p.w = f2bf(r4.w);
      *(ushort4*)&Ob[(size_t)row * N + col] = p;
    } else {
      *(float4*)&Of[(size_t)row * N + col] = r4;
    }
  }
}

// ---------------------------------------------------------------------------
// Kernel 4: logits[512, 99999] = last_h(bf16) @ emb[1:]^T  (bf16 MFMA)
// One block per 64-col n-strip, FULL M=512, 8 waves. K-loop/staging identical
// to round-3. CHANGED (round-4): epilogue's global atomicAdd to rse[512]
// (800K lane-atomics serialized on 32 cache lines -- the suspected ~200us
// stall) replaced by LDS rse_s[512] + ONE coalesced 2KB store per block
// into part[block][row]. Reduction moved to rse_loss_kernel.
// ---------------------------------------------------------------------------
#define NT    64
#define BPAD  264
#define NTILES 1563   // ceil(99999 / 64)

__global__ __launch_bounds__(512, 4) void logits_gemm(
    const unsigned short* __restrict__ Abf,  // [512,256] bf16
    const float* __restrict__ emb,           // [100000,256] f32
    float* __restrict__ out,                 // d_out: [0]=loss, [1..]=logits
    float* __restrict__ part) {              // [NTILES][512] partial sum-exp
  __shared__ short Bs[NT * BPAD];            // 33792 B
  __shared__ float rse_s[BDIM];              // 2 KB
  const int t = threadIdx.x;
  const int lane = t & 63, w = t >> 6;       // 8 waves
  const int nbase = blockIdx.x * NT;

  // ---- stage B: 64 emb rows (cols n+1), f32 -> bf16, once per block.
  {
    const int row = t >> 3;
    const int cb = (t & 7) * 4;
    int er = nbase + row + 1;
    if (er > NM1) er = NM1;  // clamp; invalid cols masked in epilogue
    const float* src = emb + (size_t)er * DDIM;
    short* dst = &Bs[row * BPAD];
#pragma unroll
    for (int j = 0; j < 8; j++) {
      const float4 v = *(const float4*)(src + j * 32 + cb);
      ushort4 p;
      p.x = f2bf(v.x); p.y = f2bf(v.y); p.z = f2bf(v.z); p.w = f2bf(v.w);
      *(ushort4*)&dst[j * 32 + cb] = p;
    }
  }
  __syncthreads();

  const int wm = w * 64;            // wave tile: 64 rows x 64 cols
  const int c = lane & 15, q = lane >> 4;

  f32x4 acc[4][4];
#pragma unroll
  for (int mi = 0; mi < 4; mi++)
#pragma unroll
    for (int ni = 0; ni < 4; ni++) acc[mi][ni] = (f32x4){0.f, 0.f, 0.f, 0.f};

#pragma unroll
  for (int ks = 0; ks < 8; ks++) {   // K = 256 in steps of 32, fully unrolled
    short8 afr[4], bfr[4];
#pragma unroll
    for (int mi = 0; mi < 4; mi++)
      afr[mi] = *(const short8*)(Abf +
          (size_t)(wm + mi * 16 + c) * DDIM + ks * 32 + q * 8);
#pragma unroll
    for (int ni = 0; ni < 4; ni++)
      bfr[ni] = *(const short8*)&Bs[(ni * 16 + c) * BPAD + ks * 32 + q * 8];
#pragma unroll
    for (int mi = 0; mi < 4; mi++)
#pragma unroll
      for (int ni = 0; ni < 4; ni++)
        acc[mi][ni] = __builtin_amdgcn_mfma_f32_16x16x32_bf16(
            afr[mi], bfr[ni], acc[mi][ni], 0, 0, 0);
  }

  // Epilogue: stores + per-row sum of exp reduced over the 16 col-lanes,
  // then LDS (no global atomics). Fast path for full tiles (all but last).
  const bool full = (nbase + NT <= NM1);
#pragma unroll
  for (int mi = 0; mi < 4; mi++) {
#pragma unroll
    for (int r = 0; r < 4; r++) {
      const int grow = wm + mi * 16 + q * 4 + r;  // C/D: row = q*4+reg
      float s = 0.f;
      if (full) {
#pragma unroll
        for (int ni = 0; ni < 4; ni++) {
          const float v = acc[mi][ni][r];
          out[1 + (size_t)grow * NM1 + nbase + ni * 16 + c] = v;
          s += __expf(v);
        }
      } else {
#pragma unroll
        for (int ni = 0; ni < 4; ni++) {
          const int col = nbase + ni * 16 + c;
          if (col < NM1) {
            const float v = acc[mi][ni][r];
            out[1 + (size_t)grow * NM1 + col] = v;
            s += __expf(v);
          }
        }
      }
#pragma unroll
      for (int msk = 1; msk < 16; msk <<= 1) s += __shfl_xor(s, msk, 64);
      if (c == 0) rse_s[grow] = s;   // distinct rows per lane -> no race
    }
  }
  __syncthreads();
  // One coalesced 2 KB store per block.
  part[(size_t)blockIdx.x * BDIM + t] = rse_s[t];
}

// ---------------------------------------------------------------------------
// Kernel 5a: per-row reduce of partial sum-exps (L2-resident, 3.2 MB) and
// lossv[b] = log(sumexp[b]) - logits[b, tar[b]-1].
// ---------------------------------------------------------------------------
__global__ __launch_bounds__(256) void rse_loss_kernel(
    const float* __restrict__ part, const float* __restrict__ out,
    const int* __restrict__ tar, float* __restrict__ lossv) {
  const int b = blockIdx.x;   // 512 blocks, one per row
  const int t = threadIdx.x;  // 256
  float s = 0.f;
  for (int j = t; j < NTILES; j += 256)
    s += part[(size_t)j * BDIM + b];
  __shared__ float red[4];
#pragma unroll
  for (int off = 32; off > 0; off >>= 1) s += __shfl_down(s, off, 64);
  if ((t & 63) == 0) red[t >> 6] = s;
  __syncthreads();
  if (t == 0) {
    const float tot = red[0] + red[1] + red[2] + red[3];
    const int tt = tar[b];
    const float lg = out[1 + (size_t)b * NM1 + (tt - 1)];
    lossv[b] = logf(tot) - lg;
  }
}

// ---------------------------------------------------------------------------
// Kernel 5b: out[0] = mean(lossv)
// ---------------------------------------------------------------------------
__global__ __launch_bounds__(512) void loss_final_kernel(
    float* __restrict__ out, const float* __restrict__ lossv) {
  __shared__ float red[512];
  const int t = threadIdx.x;
  red[t] = lossv[t];
  __syncthreads();
  for (int stride = 256; stride > 0; stride >>= 1) {
    if (t < stride) red[t] += red[t + stride];
    __syncthreads();
  }
  if (t == 0) out[0] = red[0] / (float)BDIM;
}

// ---------------------------------------------------------------------------
extern "C" void kernel_launch(void* const* d_in, const int* in_sizes, int n_in,
                              void* d_out, int out_size, void* d_ws, size_t ws_size,
                              hipStream_t stream) {
  const float* emb     = (const float*)d_in[0];
  const float* W1      = (const float*)d_in[1];
  const float* W2      = (const float*)d_in[2];
  const float* adj_in  = (const float*)d_in[3];
  const float* adj_out = (const float*)d_in[4];
  const float* mask    = (const float*)d_in[5];
  const int*   item    = (const int*)d_in[6];
  const int*   alias_  = (const int*)d_in[7];
  const int*   tar     = (const int*)d_in[8];
  float* out = (float*)d_out;

  char* ws = (char*)d_ws;
  float* av            = (float*)(ws);                 // 512*512*4 = 1 MB
  float* h1            = (float*)(ws + 1048576);       // 512*512*4 = 1 MB
  unsigned short* lasth = (unsigned short*)(ws + 2097152); // 512*256*2 = 256 KB
  float* part          = (float*)(ws + 2359296);       // 1563*512*4 = 3.2 MB
  float* lossv         = (float*)(ws + 5560320);       // 512*4

  prep_kernel<<<BDIM, 256, 0, stream>>>(emb, adj_in, adj_out, mask, item, alias_, av);
  mlp_kernel<D2, true, false><<<dim3(8, 16), dim3(16, 16), 0, stream>>>(av, W1, h1, nullptr);
  mlp_kernel<DDIM, false, true><<<dim3(4, 16), dim3(16, 16), 0, stream>>>(h1, W2, nullptr, lasth);
  logits_gemm<<<dim3(NTILES), 512, 0, stream>>>(lasth, emb, out, part);
  rse_loss_kernel<<<BDIM, 256, 0, stream>>>(part, out, tar, lossv);
  loss_final_kernel<<<1, 512, 0, stream>>>(out, lossv);
}